// Round 17
// baseline (5831.085 us; speedup 1.0000x reference)
//
#include <hip/hip_runtime.h>
#include <math.h>

// ODE-RNN forward: B=1024, T=100, D=32, H=256, MID=50 (pad 56), RK4x4.
// Round 17: R14 schedule with each role split over 2 waves -> 8-wave block
// (512 thr), 4 rows, 256 blocks = 8 waves/CU = 2/SIMD (was 1/SIMD).
// Single barrier domain, single control flow (no divergent barriers).
// A-halves: 28 mid-rows each, w1 112 regs. B-halves: 2 of 4 comps/col,
// w2 104 regs, RK4 state float2. Shared wreg[28]. DPP red16 (R8-verified),
// yc XOR-swizzle (R13/R14-verified), RNN/heads = R4 512-thread shapes.

#define NT 512

// ---- ws layout (floats): R4-proven prep ----
#define WS_WCAT 0        // [72 g][256 j][4 c]
#define WS_L1P  73728    // [64 g][128 j][4 c]
#define WS_SW1  106496   // [64 g][256 j][4 c]
#define WS_TOT  172032

// ---- LDS layout (f4 offsets) ----
#define F4_YC   0        // [4][64] swizzled y-current
#define F4_HS   256      // [4][64] linear h
#define F4_MID  512      // f32 [4][64] = 64 f4
#define F4_PR   576      // union: RNN 32x65=2080 | PH1(mu) 64x33=2112
#define F4_PH2  2688     // sig partials 32x65=2080
#define F4_XS   4768     // [4][8]
#define F4_L1O  4800     // [4][32]
#define F4_SG   4928     // [4][64]
#define F4_END  5184
#define SM_BC   (F4_END*4)        // 256
#define SM_L1B  (SM_BC+256)       // 128
#define SM_SB1  (SM_L1B+128)      // 256
#define SM_MUW  (SM_SB1+256)      // 128
#define SM_SW2  (SM_MUW+128)      // 256
#define SM_SCL  (SM_SW2+256)      // 4
#define SM_TOTF (SM_SCL+4)
#define SMEM_BYTES (SM_TOTF*4)

__device__ __forceinline__ float fma4(float a, float4 y, float4 w) {
  a = fmaf(y.x, w.x, a); a = fmaf(y.y, w.y, a);
  a = fmaf(y.z, w.z, a); a = fmaf(y.w, w.w, a);
  return a;
}
__device__ __forceinline__ float4 add4(float4 a, float4 b) {
  return make_float4(a.x+b.x, a.y+b.y, a.z+b.z, a.w+b.w);
}
__device__ __forceinline__ float tfast(float x) {
  float ax = fabsf(x);
  float e  = __expf(-2.f * ax);
  float t  = (1.f - e) * __builtin_amdgcn_rcpf(1.f + e);
  return copysignf(t, x);
}
__device__ __forceinline__ float4 tfast4(float4 v) {
  return make_float4(tfast(v.x), tfast(v.y), tfast(v.z), tfast(v.w));
}
// DPP butterfly adds (HW-verified R8): after red16 every lane of each
// aligned 16-lane group holds the group sum. Pure VALU.
template <int CTRL>
__device__ __forceinline__ float dpp_add(float v) {
  int s = __builtin_amdgcn_update_dpp(0, __float_as_int(v), CTRL, 0xF, 0xF, true);
  return v + __int_as_float(s);
}
__device__ __forceinline__ float red16(float v) {
  return dpp_add<0xB1>(dpp_add<0x4E>(dpp_add<0x141>(dpp_add<0x140>(v))));
}
// yc swizzle (verified R13/R14): logical f4 idx a stored at phys(a).
// L1 reads a=kcA*4+k -> phys k*16+(kcA^k): conflict-free; linear writes free.
__device__ __forceinline__ int ycphys(int a) {
  return ((a & 3) << 4) + ((a >> 2) ^ (a & 3));
}

__global__ void prep_w(const float* __restrict__ Wih, const float* __restrict__ Whh,
                       const float* __restrict__ l1w, const float* __restrict__ sw1,
                       float* __restrict__ ws) {
  int i = blockIdx.x * 256 + threadIdx.x;
  if (i < 73728) {                       // Wcat4
    int g = i >> 10, rem = i & 1023, j = rem >> 2, c = rem & 3;
    int k = 4 * g + c;
    ws[i] = (k < 32) ? Wih[j * 32 + k] : Whh[j * 256 + (k - 32)];
  } else if (i < 106496) {               // l1p4
    int t = i - 73728;
    int g = t >> 9, rem = t & 511, j = rem >> 2, c = rem & 3;
    ws[i] = l1w[j * 256 + 4 * g + c];
  } else if (i < WS_TOT) {               // sw1p4
    int t = i - 106496;
    int g = t >> 10, rem = t & 1023, j = rem >> 2, c = rem & 3;
    ws[i] = sw1[j * 256 + 4 * g + c];
  }
}

__global__ __attribute__((amdgpu_flat_work_group_size(NT, NT)))
void odernn_main(const float* __restrict__ dt,
                 const float* __restrict__ x,
                 const float* __restrict__ bih,
                 const float* __restrict__ bhh,
                 const float* __restrict__ ow1,
                 const float* __restrict__ ob1g,
                 const float* __restrict__ ow2,
                 const float* __restrict__ ob2g,
                 const float* __restrict__ l1bg,
                 const float* __restrict__ muwg,
                 const float* __restrict__ mubg,
                 const float* __restrict__ sb1g,
                 const float* __restrict__ sw2g,
                 const float* __restrict__ sb2g,
                 const float* __restrict__ ws,
                 float* __restrict__ out) {
  extern __shared__ __align__(16) float sm[];
  float4* f4 = (float4*)sm;
  float* midS = sm + F4_MID * 4;                 // f32 [4][64]
  float2* yc2 = (float2*)(f4 + F4_YC);
  float2* hs2 = (float2*)(f4 + F4_HS);
  const float4* mid4 = (const float4*)midS;      // [4][16]
  const int tid = threadIdx.x;
  const int wv = tid >> 6, ln = tid & 63;
  const int b0 = blockIdx.x * 4;

  const int pair = wv >> 2;                      // 0,1 -> rows {0,1},{2,3}
  const int role = wv & 3;                       // 0,1 = A-half; 2,3 = B-half
  const bool isA = role < 2;
  const int ra = pair * 2, rb = ra + 1;

  const float4* wcat4 = (const float4*)(ws + WS_WCAT);
  const float4* l1w4  = (const float4*)(ws + WS_L1P);
  const float4* sw14  = (const float4*)(ws + WS_SW1);
  const float4* xg4   = (const float4*)x;

  // ---- role-resident weights in a SHARED register array (<=112 regs) ----
  float4 wreg[28];
  float  obr[7];
  const int qA = ln >> 4, kcA = ln & 15;         // A lane shape
  const int bC = role - 2;                       // B comp-half (0: xy, 1: zw)
  if (isA) {
    const int aIdx = role;                       // 0 or 1 -> j base
#pragma unroll
    for (int jj = 0; jj < 7; ++jj) {
      int j = aIdx * 28 + qA * 7 + jj;
      obr[jj] = (j < 50) ? ob1g[j] : 0.f;
#pragma unroll
      for (int f = 0; f < 4; ++f)
        wreg[jj * 4 + f] = (j < 50)
            ? *(const float4*)&ow1[j * 256 + kcA * 16 + 4 * f]
            : make_float4(0.f, 0.f, 0.f, 0.f);
    }
  } else {
#pragma unroll
    for (int c = 0; c < 2; ++c) {
      int col = 4 * ln + 2 * bC + c;
      obr[c] = ob2g[col];
#pragma unroll
      for (int g = 0; g < 13; ++g) {
        float t0 = (4*g+0 < 50) ? ow2[col*50 + 4*g+0] : 0.f;
        float t1 = (4*g+1 < 50) ? ow2[col*50 + 4*g+1] : 0.f;
        float t2 = (4*g+2 < 50) ? ow2[col*50 + 4*g+2] : 0.f;
        float t3 = (4*g+3 < 50) ? ow2[col*50 + 4*g+3] : 0.f;
        wreg[c * 13 + g] = make_float4(t0, t1, t2, t3);
      }
    }
    wreg[26] = make_float4(0,0,0,0);
    wreg[27] = make_float4(0,0,0,0);
#pragma unroll
    for (int jj = 2; jj < 7; ++jj) obr[jj] = 0.f;
  }

  // ---- prologue: biases, x, scl, h=0 ----
  if (tid < 256) { sm[SM_BC + tid] = bih[tid] + bhh[tid];
                   sm[SM_SB1 + tid] = sb1g[tid];
                   sm[SM_SW2 + tid] = sw2g[tid]; }
  if (tid < 128) { sm[SM_L1B + tid] = l1bg[tid]; sm[SM_MUW + tid] = muwg[tid]; }
  if (tid < 256) f4[F4_HS + tid] = make_float4(0.f, 0.f, 0.f, 0.f);
  if (tid < 32) {
    int r = tid >> 3, g = tid & 7;
    f4[F4_XS + tid] = xg4[((size_t)(b0 + r) * 100) * 8 + g];
  } else if (tid < 36) {
    int r = tid - 32;
    const float* dp = dt + ((size_t)(b0 + r) * 100) * 2;
    sm[SM_SCL + r] = (dp[1] - dp[0]) * (1.f / 24.f);
  }
  __syncthreads();

  const float mubv = mubg[0], sb2v = sb2g[0];
  const float4* bc4  = (const float4*)(sm + SM_BC);
  const float4* l1b4 = (const float4*)(sm + SM_L1B);
  const float4* sb14 = (const float4*)(sm + SM_SB1);
  const float4* muw4 = (const float4*)(sm + SM_MUW);
  const float4* sw24 = (const float4*)(sm + SM_SW2);

  const int physW = ycphys(ln);
  float2 hA2, hB2, acA2, acB2;                   // B-halves only
  float sclA = 0.f, sclB = 0.f;

  for (int t = 0; t < 100; ++t) {
    // ===== RNN partials (512 thr, 4 rows; R4-proven shape)
    {
      const int jq = tid & 63, kc = tid >> 6;
      float4 a0 = make_float4(0,0,0,0), a1 = a0, a2 = a0, a3 = a0;
#pragma unroll 3
      for (int gg = 0; gg < 9; ++gg) {
        int g = kc * 9 + gg;
        float4 w0 = wcat4[g * 256 + 4 * jq + 0];
        float4 w1 = wcat4[g * 256 + 4 * jq + 1];
        float4 w2 = wcat4[g * 256 + 4 * jq + 2];
        float4 w3 = wcat4[g * 256 + 4 * jq + 3];
        float4 y0 = (g < 8) ? f4[F4_XS + g]      : f4[F4_HS + (g - 8)];
        float4 y1 = (g < 8) ? f4[F4_XS + 8 + g]  : f4[F4_HS + 64 + (g - 8)];
        float4 y2 = (g < 8) ? f4[F4_XS + 16 + g] : f4[F4_HS + 128 + (g - 8)];
        float4 y3 = (g < 8) ? f4[F4_XS + 24 + g] : f4[F4_HS + 192 + (g - 8)];
        a0.x = fma4(a0.x, y0, w0); a0.y = fma4(a0.y, y0, w1);
        a0.z = fma4(a0.z, y0, w2); a0.w = fma4(a0.w, y0, w3);
        a1.x = fma4(a1.x, y1, w0); a1.y = fma4(a1.y, y1, w1);
        a1.z = fma4(a1.z, y1, w2); a1.w = fma4(a1.w, y1, w3);
        a2.x = fma4(a2.x, y2, w0); a2.y = fma4(a2.y, y2, w1);
        a2.z = fma4(a2.z, y2, w2); a2.w = fma4(a2.w, y2, w3);
        a3.x = fma4(a3.x, y3, w0); a3.y = fma4(a3.y, y3, w1);
        a3.z = fma4(a3.z, y3, w2); a3.w = fma4(a3.w, y3, w3);
      }
      f4[F4_PR + (kc * 4 + 0) * 65 + jq] = a0;
      f4[F4_PR + (kc * 4 + 1) * 65 + jq] = a1;
      f4[F4_PR + (kc * 4 + 2) * 65 + jq] = a2;
      f4[F4_PR + (kc * 4 + 3) * 65 + jq] = a3;
    }
    __syncthreads();
    // ===== RNN reduce -> yc (swizzled)
    if (tid < 256) {
      const int r = tid >> 6, jq = tid & 63;
      float4 v = bc4[jq];
#pragma unroll
      for (int kc = 0; kc < 8; ++kc)
        v = add4(v, f4[F4_PR + (kc * 4 + r) * 65 + jq]);
      float4 hold = f4[F4_HS + r * 64 + jq];
      f4[F4_YC + r * 64 + ycphys(jq)] = add4(hold, tfast4(v));
    }
    __syncthreads();

    // ===== eval: 33 phases; A-halves L1(row ph&1), B-halves L2(other row)
#pragma unroll 1
    for (int ph = 0; ph <= 32; ++ph) {
      if (isA) {
        if (ph < 32) {
          const int row = ra + (ph & 1);
          float4 y0 = f4[F4_YC + row * 64 + 0 * 16 + (kcA ^ 0)];
          float4 y1 = f4[F4_YC + row * 64 + 1 * 16 + (kcA ^ 1)];
          float4 y2 = f4[F4_YC + row * 64 + 2 * 16 + (kcA ^ 2)];
          float4 y3 = f4[F4_YC + row * 64 + 3 * 16 + (kcA ^ 3)];
          float p[7];
#pragma unroll
          for (int jj = 0; jj < 7; ++jj) {
            float s = 0.f;
            s = fma4(s, y0, wreg[jj * 4 + 0]); s = fma4(s, y1, wreg[jj * 4 + 1]);
            s = fma4(s, y2, wreg[jj * 4 + 2]); s = fma4(s, y3, wreg[jj * 4 + 3]);
            p[jj] = s;
          }
#pragma unroll
          for (int jj = 0; jj < 7; ++jj) p[jj] = red16(p[jj]);
          if (kcA == 0) {
            const int jb = role * 28 + qA * 7;
#pragma unroll
            for (int jj = 0; jj < 7; ++jj)
              midS[row * 64 + jb + jj] = tfast(p[jj] + obr[jj]);
          }
        } else if (t < 99 && wv == 0) {          // stage next x / scl
          if (ln < 32) {
            int r = ln >> 3, g = ln & 7;
            f4[F4_XS + ln] = xg4[((size_t)(b0 + r) * 100 + t + 1) * 8 + g];
          } else if (ln < 36) {
            int r = ln - 32;
            const float* dp = dt + ((size_t)(b0 + r) * 100 + t + 1) * 2;
            sm[SM_SCL + r] = (dp[1] - dp[0]) * (1.f / 24.f);
          }
        }
      } else {
        if (ph == 0) {
          hA2 = yc2[(ra * 64 + physW) * 2 + bC];
          hB2 = yc2[(rb * 64 + physW) * 2 + bC];
          acA2 = make_float2(0.f, 0.f); acB2 = acA2;
          sclA = sm[SM_SCL + ra]; sclB = sm[SM_SCL + rb];
        } else {
          const int rr = (ph - 1) & 1, e = (ph - 1) >> 1;
          const int row = ra + rr;
          float2& h2 = rr ? hB2 : hA2;
          float2& ac2 = rr ? acB2 : acA2;
          const float sc = rr ? sclB : sclA;
          float ax = 0.f, ay = 0.f;
#pragma unroll
          for (int g = 0; g < 13; ++g) {
            float4 m = mid4[row * 16 + g];
            ax = fma4(ax, m, wreg[0 * 13 + g]);
            ay = fma4(ay, m, wreg[1 * 13 + g]);
          }
          float kx = (ax + obr[0]) * sc, ky = (ay + obr[1]) * sc;
          const int s = e & 3;
          float2 ycw;
          if (s == 0) {
            ac2 = make_float2(kx, ky);
            ycw = make_float2(fmaf(0.125f, kx, h2.x), fmaf(0.125f, ky, h2.y));
          } else if (s == 1) {
            ac2.x = fmaf(2.f, kx, ac2.x); ac2.y = fmaf(2.f, ky, ac2.y);
            ycw = make_float2(fmaf(0.125f, kx, h2.x), fmaf(0.125f, ky, h2.y));
          } else if (s == 2) {
            ac2.x = fmaf(2.f, kx, ac2.x); ac2.y = fmaf(2.f, ky, ac2.y);
            ycw = make_float2(fmaf(0.25f, kx, h2.x), fmaf(0.25f, ky, h2.y));
          } else {
            h2.x = fmaf(0.25f / 6.f, ac2.x + kx, h2.x);
            h2.y = fmaf(0.25f / 6.f, ac2.y + ky, h2.y);
            ycw = h2;
          }
          yc2[(row * 64 + physW) * 2 + bC] = ycw;
          if (e == 15) hs2[(row * 64 + ln) * 2 + bC] = h2;
        }
      }
      __syncthreads();
    }

    // ===== heads partials (512 thr; R4-proven shapes)
    {
      const int cq = tid & 31, kc = tid >> 5;    // mu: 16 kc x 4 g
      float4 c0 = make_float4(0,0,0,0), c1 = c0, c2 = c0, c3 = c0;
#pragma unroll 2
      for (int g = 0; g < 4; ++g) {
        int kg = kc * 4 + g;
        float4 w0 = l1w4[kg * 128 + 4 * cq + 0];
        float4 w1 = l1w4[kg * 128 + 4 * cq + 1];
        float4 w2 = l1w4[kg * 128 + 4 * cq + 2];
        float4 w3 = l1w4[kg * 128 + 4 * cq + 3];
        float4 y0 = f4[F4_HS + kg],       y1 = f4[F4_HS + 64 + kg];
        float4 y2 = f4[F4_HS + 128 + kg], y3 = f4[F4_HS + 192 + kg];
        c0.x = fma4(c0.x, y0, w0); c0.y = fma4(c0.y, y0, w1);
        c0.z = fma4(c0.z, y0, w2); c0.w = fma4(c0.w, y0, w3);
        c1.x = fma4(c1.x, y1, w0); c1.y = fma4(c1.y, y1, w1);
        c1.z = fma4(c1.z, y1, w2); c1.w = fma4(c1.w, y1, w3);
        c2.x = fma4(c2.x, y2, w0); c2.y = fma4(c2.y, y2, w1);
        c2.z = fma4(c2.z, y2, w2); c2.w = fma4(c2.w, y2, w3);
        c3.x = fma4(c3.x, y3, w0); c3.y = fma4(c3.y, y3, w1);
        c3.z = fma4(c3.z, y3, w2); c3.w = fma4(c3.w, y3, w3);
      }
      f4[F4_PR + (kc * 4 + 0) * 33 + cq] = c0;
      f4[F4_PR + (kc * 4 + 1) * 33 + cq] = c1;
      f4[F4_PR + (kc * 4 + 2) * 33 + cq] = c2;
      f4[F4_PR + (kc * 4 + 3) * 33 + cq] = c3;
    }
    {
      const int cq = tid & 63, kc = tid >> 6;    // sig: 8 kc x 8 g
      float4 d0 = make_float4(0,0,0,0), d1 = d0, d2 = d0, d3 = d0;
#pragma unroll 2
      for (int g = 0; g < 8; ++g) {
        int kg = kc * 8 + g;
        float4 w0 = sw14[kg * 256 + 4 * cq + 0];
        float4 w1 = sw14[kg * 256 + 4 * cq + 1];
        float4 w2 = sw14[kg * 256 + 4 * cq + 2];
        float4 w3 = sw14[kg * 256 + 4 * cq + 3];
        float4 y0 = f4[F4_HS + kg],       y1 = f4[F4_HS + 64 + kg];
        float4 y2 = f4[F4_HS + 128 + kg], y3 = f4[F4_HS + 192 + kg];
        d0.x = fma4(d0.x, y0, w0); d0.y = fma4(d0.y, y0, w1);
        d0.z = fma4(d0.z, y0, w2); d0.w = fma4(d0.w, y0, w3);
        d1.x = fma4(d1.x, y1, w0); d1.y = fma4(d1.y, y1, w1);
        d1.z = fma4(d1.z, y1, w2); d1.w = fma4(d1.w, y1, w3);
        d2.x = fma4(d2.x, y2, w0); d2.y = fma4(d2.y, y2, w1);
        d2.z = fma4(d2.z, y2, w2); d2.w = fma4(d2.w, y2, w3);
        d3.x = fma4(d3.x, y3, w0); d3.y = fma4(d3.y, y3, w1);
        d3.z = fma4(d3.z, y3, w2); d3.w = fma4(d3.w, y3, w3);
      }
      f4[F4_PH2 + (kc * 4 + 0) * 65 + cq] = d0;
      f4[F4_PH2 + (kc * 4 + 1) * 65 + cq] = d1;
      f4[F4_PH2 + (kc * 4 + 2) * 65 + cq] = d2;
      f4[F4_PH2 + (kc * 4 + 3) * 65 + cq] = d3;
    }
    __syncthreads();
    // ===== head reduces
    if (tid < 128) {
      int r = tid >> 5, cq = tid & 31;
      float4 v = l1b4[cq];
#pragma unroll
      for (int kc = 0; kc < 16; ++kc)
        v = add4(v, f4[F4_PR + (kc * 4 + r) * 33 + cq]);
      f4[F4_L1O + r * 32 + cq] =
          make_float4(fmaxf(v.x, 0.f), fmaxf(v.y, 0.f),
                      fmaxf(v.z, 0.f), fmaxf(v.w, 0.f));
    } else if (tid < 384) {
      int t2 = tid - 128;
      int r = t2 >> 6, cq = t2 & 63;
      float4 v = sb14[cq];
#pragma unroll
      for (int kc = 0; kc < 8; ++kc)
        v = add4(v, f4[F4_PH2 + (kc * 4 + r) * 65 + cq]);
      f4[F4_SG + r * 64 + cq] = tfast4(v);
    }
    __syncthreads();
    // ===== final dots: waves 0-3 -> mu rows 0-3, waves 4-7 -> sig rows 0-3
    if (wv < 4) {
      float pm = 0.f;
      if (ln < 32) {
        float4 l = f4[F4_L1O + wv * 32 + ln];
        float4 w = muw4[ln];
        pm = l.x * w.x + l.y * w.y + l.z * w.z + l.w * w.w;
      }
#pragma unroll
      for (int off = 32; off > 0; off >>= 1) pm += __shfl_down(pm, off);
      if (ln == 0) out[(size_t)(b0 + wv) * 100 + t] = pm + mubv;
    } else {
      const int r = wv - 4;
      float4 sv = f4[F4_SG + r * 64 + ln];
      float4 w2v = sw24[ln];
      float ps = sv.x * w2v.x + sv.y * w2v.y + sv.z * w2v.z + sv.w * w2v.w;
#pragma unroll
      for (int off = 32; off > 0; off >>= 1) ps += __shfl_down(ps, off);
      if (ln == 0) {
        float z = ps + sb2v;
        float sp = fmaxf(z, 0.f) + log1pf(expf(-fabsf(z)));
        out[(size_t)102400 + (size_t)(b0 + r) * 100 + t] = sp;
      }
    }
    __syncthreads();
  }
}

extern "C" void kernel_launch(void* const* d_in, const int* in_sizes, int n_in,
                              void* d_out, int out_size, void* d_ws, size_t ws_size,
                              hipStream_t stream) {
  const float* dt  = (const float*)d_in[0];
  const float* x   = (const float*)d_in[1];
  const float* Wih = (const float*)d_in[2];
  const float* bih = (const float*)d_in[3];
  const float* Whh = (const float*)d_in[4];
  const float* bhh = (const float*)d_in[5];
  const float* ow1 = (const float*)d_in[6];
  const float* ob1 = (const float*)d_in[7];
  const float* ow2 = (const float*)d_in[8];
  const float* ob2 = (const float*)d_in[9];
  const float* l1w = (const float*)d_in[10];
  const float* l1b = (const float*)d_in[11];
  const float* muw = (const float*)d_in[12];
  const float* mub = (const float*)d_in[13];
  const float* sw1 = (const float*)d_in[14];
  const float* sb1 = (const float*)d_in[15];
  const float* sw2 = (const float*)d_in[16];
  const float* sb2 = (const float*)d_in[17];
  float* ws  = (float*)d_ws;
  float* out = (float*)d_out;

  hipFuncSetAttribute((const void*)odernn_main,
                      hipFuncAttributeMaxDynamicSharedMemorySize, SMEM_BYTES);

  prep_w<<<WS_TOT / 256, 256, 0, stream>>>(Wih, Whh, l1w, sw1, ws);
  odernn_main<<<256, NT, SMEM_BYTES, stream>>>(dt, x, bih, bhh, ow1, ob1, ow2, ob2,
                                               l1b, muw, mub, sb1, sw2, sb2, ws, out);
}